// Round 1
// baseline (577.067 us; speedup 1.0000x reference)
//
#include <hip/hip_runtime.h>
#include <math.h>

#define NSNPS  500000
#define NGENES 20000
#define NNODES 600000
#define NEDGES 320000
#define BB     16
#define NFILT  8

// rsqrt(1 + 1e-5)
#define BN_SCALE 0.99999500003749968f

__device__ __forceinline__ float gelu_erf(float x) {
    return 0.5f * x * (1.0f + erff(x * 0.70710678118654752f));
}
__device__ __forceinline__ float sigmoidf_(float x) {
    return 1.0f / (1.0f + expf(-x));
}

// ---------------------------------------------------------------------------
// filters [NFILT, NSNPS] -> filtersT [NSNPS, NFILT]   (coalesced reads)
__global__ __launch_bounds__(256) void k_transpose(const float* __restrict__ filters,
                                                   float* __restrict__ filtersT) {
    int idx = blockIdx.x * 256 + threadIdx.x;
    if (idx >= NFILT * NSNPS) return;
    int f = idx / NSNPS;
    int n = idx - f * NSNPS;
    filtersT[n * NFILT + f] = filters[idx];
}

// ---------------------------------------------------------------------------
// node_off[g] = lower_bound(gene_of_node, g), g in [0, NGENES]
__global__ __launch_bounds__(256) void k_node_off(const int* __restrict__ gene_of_node,
                                                  int* __restrict__ node_off) {
    int g = blockIdx.x * 256 + threadIdx.x;
    if (g > NGENES) return;
    int lo = 0, hi = NNODES;
    while (lo < hi) {
        int mid = (lo + hi) >> 1;
        if (gene_of_node[mid] < g) lo = mid + 1; else hi = mid;
    }
    node_off[g] = lo;
}

// ---------------------------------------------------------------------------
__global__ __launch_bounds__(256) void k_zero(int* __restrict__ deg, float* __restrict__ g_h) {
    int i = blockIdx.x * 256 + threadIdx.x;
    if (i < NGENES) deg[i] = 0;
    if (i < BB * NFILT) g_h[i] = 0.0f;
}

__global__ __launch_bounds__(256) void k_deg(const int* __restrict__ edge_dst,
                                             int* __restrict__ deg) {
    int e = blockIdx.x * 256 + threadIdx.x;
    if (e >= NEDGES) return;
    atomicAdd(&deg[edge_dst[e]], 1);
}

// single-block exclusive scan over deg[NGENES] -> csr_off, cursor
__global__ __launch_bounds__(1024) void k_scan(const int* __restrict__ deg,
                                               int* __restrict__ csr_off,
                                               int* __restrict__ cursor) {
    __shared__ int sums[1024];
    int t = threadIdx.x;
    const int CH = (NGENES + 1023) / 1024;   // 20
    int base = t * CH;
    int s = 0;
    for (int i = 0; i < CH; i++) {
        int idx = base + i;
        if (idx < NGENES) s += deg[idx];
    }
    sums[t] = s;
    __syncthreads();
    for (int off = 1; off < 1024; off <<= 1) {
        int v = (t >= off) ? sums[t - off] : 0;
        __syncthreads();
        sums[t] += v;
        __syncthreads();
    }
    int run = (t == 0) ? 0 : sums[t - 1];
    for (int i = 0; i < CH; i++) {
        int idx = base + i;
        if (idx < NGENES) {
            csr_off[idx] = run;
            cursor[idx]  = run;
            run += deg[idx];
        }
    }
    if (t == 1023) csr_off[NGENES] = sums[1023];
}

__global__ __launch_bounds__(256) void k_scatter(const int* __restrict__ edge_src,
                                                 const int* __restrict__ edge_dst,
                                                 int* __restrict__ cursor,
                                                 int* __restrict__ csr_src) {
    int e = blockIdx.x * 256 + threadIdx.x;
    if (e >= NEDGES) return;
    int p = atomicAdd(&cursor[edge_dst[e]], 1);
    csr_src[p] = edge_src[e];
}

// ---------------------------------------------------------------------------
// SNP -> gene segment sum.  One wave per (gene, batch); lane = sub*8 + f.
// h[b][g][f] = sum_{nodes of g} snp[b][sid] * filtersT[sid][f]
__global__ __launch_bounds__(256) void k_snp2gene(const float* __restrict__ snp,
                                                  const int* __restrict__ snp_ids,
                                                  const int* __restrict__ node_off,
                                                  const float* __restrict__ filtersT,
                                                  float* __restrict__ h) {
    int wid = blockIdx.x * 4 + (threadIdx.x >> 6);       // 0 .. NGENES*BB-1
    int g = wid >> 4;
    int b = wid & 15;
    int lane = threadIdx.x & 63;
    int f = lane & 7;
    int sub = lane >> 3;
    int s = node_off[g], e = node_off[g + 1];
    const float* snpb = snp + (size_t)b * NSNPS;
    float acc = 0.0f;
    for (int i = s + sub; i < e; i += 8) {
        int sid = snp_ids[i];
        acc += snpb[sid] * filtersT[sid * NFILT + f];
    }
    acc += __shfl_xor(acc, 8, 64);
    acc += __shfl_xor(acc, 16, 64);
    acc += __shfl_xor(acc, 32, 64);
    if (lane < 8) h[((size_t)(b * NGENES + g)) * NFILT + f] = acc;
}

// ---------------------------------------------------------------------------
// Fused GIN layer: agg (CSR gather) + (1+eps)*h + MLP(8->16->8) + BN + GELU
__global__ __launch_bounds__(256) void k_gin(const float* __restrict__ hin,
                                             float* __restrict__ hout,
                                             const int* __restrict__ csr_off,
                                             const int* __restrict__ csr_src,
                                             const float* __restrict__ eps_l,
                                             const float* __restrict__ W1,
                                             const float* __restrict__ b1,
                                             const float* __restrict__ g1,
                                             const float* __restrict__ bt1,
                                             const float* __restrict__ W2,
                                             const float* __restrict__ b2,
                                             const float* __restrict__ g2,
                                             const float* __restrict__ bt2) {
    __shared__ float sW1[128], sb1[16], sg1[16], sbt1[16];
    __shared__ float sW2[128], sb2[8], sg2[8], sbt2[8];
    int t = threadIdx.x;
    if (t < 128) { sW1[t] = W1[t]; sW2[t] = W2[t]; }
    if (t < 16)  { sb1[t] = b1[t]; sg1[t] = g1[t]; sbt1[t] = bt1[t]; }
    if (t < 8)   { sb2[t] = b2[t]; sg2[t] = g2[t]; sbt2[t] = bt2[t]; }
    __syncthreads();

    int g = blockIdx.x * 256 + t;
    if (g >= NGENES) return;
    int b = blockIdx.y;

    float z[8];
    const float* hr = hin + ((size_t)b * NGENES + g) * NFILT;
    float epsv = 1.0f + eps_l[0];
    #pragma unroll
    for (int f = 0; f < 8; f++) z[f] = epsv * hr[f];

    int s = csr_off[g], e = csr_off[g + 1];
    const float* hb = hin + (size_t)b * NGENES * NFILT;
    for (int k = s; k < e; k++) {
        const float* hs = hb + (size_t)csr_src[k] * NFILT;
        const float4* hs4 = (const float4*)hs;
        float4 v0 = hs4[0], v1 = hs4[1];
        z[0] += v0.x; z[1] += v0.y; z[2] += v0.z; z[3] += v0.w;
        z[4] += v1.x; z[5] += v1.y; z[6] += v1.z; z[7] += v1.w;
    }

    float o[8];
    #pragma unroll
    for (int f = 0; f < 8; f++) o[f] = sb2[f];
    #pragma unroll
    for (int j = 0; j < 16; j++) {
        float s1 = sb1[j];
        #pragma unroll
        for (int i = 0; i < 8; i++) s1 += z[i] * sW1[i * 16 + j];
        s1 = s1 * BN_SCALE * sg1[j] + sbt1[j];
        s1 = gelu_erf(s1);
        #pragma unroll
        for (int f = 0; f < 8; f++) o[f] += s1 * sW2[j * 8 + f];
    }
    float* ho = hout + ((size_t)b * NGENES + g) * NFILT;
    #pragma unroll
    for (int f = 0; f < 8; f++) {
        float v = o[f] * BN_SCALE * sg2[f] + sbt2[f];
        ho[f] = gelu_erf(v);
    }
}

// ---------------------------------------------------------------------------
// Attentive readout: w = sigmoid((h@Wk+bk)@Wq); v = h@Wv+bv; g_h += v*w
__global__ __launch_bounds__(256) void k_readout(const float* __restrict__ h,
                                                 const float* __restrict__ Wk,
                                                 const float* __restrict__ bk,
                                                 const float* __restrict__ Wq,
                                                 const float* __restrict__ Wv,
                                                 const float* __restrict__ bv,
                                                 float* __restrict__ w_out,
                                                 float* __restrict__ g_h) {
    __shared__ float sWk[64], sWv[64], sbk[8], sbv[8], sWq[8];
    __shared__ float lds[4][8];
    int t = threadIdx.x;
    if (t < 64) { sWk[t] = Wk[t]; sWv[t] = Wv[t]; }
    if (t < 8)  { sbk[t] = bk[t]; sbv[t] = bv[t]; sWq[t] = Wq[t]; }
    __syncthreads();

    int g = blockIdx.x * 256 + t;
    int b = blockIdx.y;
    float contrib[8];
    #pragma unroll
    for (int f = 0; f < 8; f++) contrib[f] = 0.0f;

    if (g < NGENES) {
        const float* hr = h + ((size_t)b * NGENES + g) * NFILT;
        float hv[8];
        #pragma unroll
        for (int i = 0; i < 8; i++) hv[i] = hr[i];
        float q = 0.0f;
        #pragma unroll
        for (int j = 0; j < 8; j++) {
            float key = sbk[j];
            #pragma unroll
            for (int i = 0; i < 8; i++) key += hv[i] * sWk[i * 8 + j];
            q += key * sWq[j];
        }
        float w = sigmoidf_(q);
        w_out[(size_t)b * NGENES + g] = w;
        #pragma unroll
        for (int f = 0; f < 8; f++) {
            float v = sbv[f];
            #pragma unroll
            for (int i = 0; i < 8; i++) v += hv[i] * sWv[i * 8 + f];
            contrib[f] = v * w;
        }
    }
    // wave reduce (all lanes participate)
    #pragma unroll
    for (int f = 0; f < 8; f++) {
        #pragma unroll
        for (int m = 1; m < 64; m <<= 1) contrib[f] += __shfl_xor(contrib[f], m, 64);
    }
    int wave = t >> 6, lane = t & 63;
    if (lane < 8) lds[wave][lane] = contrib[lane];
    __syncthreads();
    if (t < 8) {
        float s = lds[0][t] + lds[1][t] + lds[2][t] + lds[3][t];
        atomicAdd(&g_h[b * NFILT + t], s);
    }
}

// ---------------------------------------------------------------------------
// Head MLP: g_h[16,8] -> 64 -> 16 -> 1, single block
__global__ __launch_bounds__(1024) void k_head(const float* __restrict__ g_h,
                                               const float* __restrict__ Wp1, const float* __restrict__ bp1,
                                               const float* __restrict__ gp1, const float* __restrict__ btp1,
                                               const float* __restrict__ Wp2, const float* __restrict__ bp2,
                                               const float* __restrict__ gp2, const float* __restrict__ btp2,
                                               const float* __restrict__ Wp3, const float* __restrict__ bp3,
                                               float* __restrict__ preds) {
    __shared__ float sgh[128];
    __shared__ float z1[16 * 64];
    __shared__ float z2[16 * 16];
    int t = threadIdx.x;
    if (t < 128) sgh[t] = g_h[t];
    __syncthreads();
    {   // stage 1: 16 x 64
        int b = t >> 6, j = t & 63;
        float s = bp1[j];
        #pragma unroll
        for (int k = 0; k < 8; k++) s += sgh[b * 8 + k] * Wp1[k * 64 + j];
        s = s * BN_SCALE * gp1[j] + btp1[j];
        z1[b * 64 + j] = gelu_erf(s);
    }
    __syncthreads();
    if (t < 256) {   // stage 2: 16 x 16
        int b = t >> 4, j = t & 15;
        float s = bp2[j];
        for (int k = 0; k < 64; k++) s += z1[b * 64 + k] * Wp2[k * 16 + j];
        s = s * BN_SCALE * gp2[j] + btp2[j];
        z2[b * 16 + j] = gelu_erf(s);
    }
    __syncthreads();
    if (t < 16) {    // stage 3: 16 x 1
        float s = bp3[0];
        #pragma unroll
        for (int k = 0; k < 16; k++) s += z2[t * 16 + k] * Wp3[k];
        preds[t] = s;
    }
}

// ---------------------------------------------------------------------------
// copy filters -> d_out (output 1), vectorized
__global__ __launch_bounds__(256) void k_copy4(const float4* __restrict__ src,
                                               float4* __restrict__ dst, int n4) {
    int i = blockIdx.x * 256 + threadIdx.x;
    if (i < n4) dst[i] = src[i];
}

// ---------------------------------------------------------------------------
extern "C" void kernel_launch(void* const* d_in, const int* in_sizes, int n_in,
                              void* d_out, int out_size, void* d_ws, size_t ws_size,
                              hipStream_t stream) {
    const float* snp          = (const float*)d_in[0];
    const int*   snp_ids      = (const int*)  d_in[1];
    const int*   gene_of_node = (const int*)  d_in[2];
    const int*   edge_src     = (const int*)  d_in[3];
    const int*   edge_dst     = (const int*)  d_in[4];
    const float* filters      = (const float*)d_in[5];
    const float* eps          = (const float*)d_in[6];
    const float* W1  = (const float*)d_in[7];
    const float* b1  = (const float*)d_in[8];
    const float* g1  = (const float*)d_in[9];
    const float* bt1 = (const float*)d_in[10];
    const float* W2  = (const float*)d_in[11];
    const float* b2  = (const float*)d_in[12];
    const float* g2  = (const float*)d_in[13];
    const float* bt2 = (const float*)d_in[14];
    const float* Wk  = (const float*)d_in[15];
    const float* bk  = (const float*)d_in[16];
    const float* Wq  = (const float*)d_in[17];
    const float* Wv  = (const float*)d_in[18];
    const float* bv  = (const float*)d_in[19];
    const float* Wp1 = (const float*)d_in[20];
    const float* bp1 = (const float*)d_in[21];
    const float* gp1 = (const float*)d_in[22];
    const float* btp1= (const float*)d_in[23];
    const float* Wp2 = (const float*)d_in[24];
    const float* bp2 = (const float*)d_in[25];
    const float* gp2 = (const float*)d_in[26];
    const float* btp2= (const float*)d_in[27];
    const float* Wp3 = (const float*)d_in[28];
    const float* bp3 = (const float*)d_in[29];

    float* out        = (float*)d_out;
    float* out_preds  = out;                 // [16]
    float* out_filt   = out + 16;            // [8, 500000]
    float* out_w      = out + 16 + NFILT * NSNPS;  // [16, 20000]

    // filtersT scratch lives in the d_out filters region (exactly 16 MB);
    // overwritten by the real copy at the very end.
    float* filtersT = out_filt;

    // workspace layout
    char* ws = (char*)d_ws;
    size_t off = 0;
    float* h0 = (float*)(ws + off); off += (size_t)BB * NGENES * NFILT * 4;      // 10.24 MB
    float* h1 = (float*)(ws + off); off += (size_t)BB * NGENES * NFILT * 4;      // 10.24 MB
    int* node_off = (int*)(ws + off); off += ((NGENES + 1) * 4 + 255) / 256 * 256;
    int* deg      = (int*)(ws + off); off += (NGENES * 4 + 255) / 256 * 256;
    int* csr_off  = (int*)(ws + off); off += ((NGENES + 1) * 4 + 255) / 256 * 256;
    int* cursor   = (int*)(ws + off); off += (NGENES * 4 + 255) / 256 * 256;
    int* csr_src  = (int*)(ws + off); off += (size_t)NEDGES * 4;
    float* g_h    = (float*)(ws + off); off += 256;

    // 1. transpose filters into d_out scratch
    k_transpose<<<(NFILT * NSNPS + 255) / 256, 256, 0, stream>>>(filters, filtersT);
    // 2. gene node offsets (sorted gene_of_node)
    k_node_off<<<(NGENES + 1 + 255) / 256, 256, 0, stream>>>(gene_of_node, node_off);
    // 3. CSR build
    k_zero<<<(NGENES + 255) / 256, 256, 0, stream>>>(deg, g_h);
    k_deg<<<(NEDGES + 255) / 256, 256, 0, stream>>>(edge_dst, deg);
    k_scan<<<1, 1024, 0, stream>>>(deg, csr_off, cursor);
    k_scatter<<<(NEDGES + 255) / 256, 256, 0, stream>>>(edge_src, edge_dst, cursor, csr_src);
    // 4. SNP -> gene readout (one wave per (gene,batch))
    k_snp2gene<<<(NGENES * BB) / 4, 256, 0, stream>>>(snp, snp_ids, node_off, filtersT, h0);
    // 5. GIN layers
    dim3 grid_row((NGENES + 255) / 256, BB);
    k_gin<<<grid_row, 256, 0, stream>>>(h0, h1, csr_off, csr_src, eps + 0,
                                        W1 + 0 * 128, b1 + 0 * 16, g1 + 0 * 16, bt1 + 0 * 16,
                                        W2 + 0 * 128, b2 + 0 * 8, g2 + 0 * 8, bt2 + 0 * 8);
    k_gin<<<grid_row, 256, 0, stream>>>(h1, h0, csr_off, csr_src, eps + 1,
                                        W1 + 1 * 128, b1 + 1 * 16, g1 + 1 * 16, bt1 + 1 * 16,
                                        W2 + 1 * 128, b2 + 1 * 8, g2 + 1 * 8, bt2 + 1 * 8);
    // 6. attentive readout (writes w output + g_h)
    k_readout<<<grid_row, 256, 0, stream>>>(h0, Wk, bk, Wq, Wv, bv, out_w, g_h);
    // 7. head MLP -> preds
    k_head<<<1, 1024, 0, stream>>>(g_h, Wp1, bp1, gp1, btp1, Wp2, bp2, gp2, btp2, Wp3, bp3, out_preds);
    // 8. final filters passthrough copy (overwrites the filtersT scratch)
    k_copy4<<<(NFILT * NSNPS / 4 + 255) / 256, 256, 0, stream>>>((const float4*)filters,
                                                                 (float4*)out_filt,
                                                                 NFILT * NSNPS / 4);
}

// Round 2
// 474.065 us; speedup vs baseline: 1.2173x; 1.2173x over previous
//
#include <hip/hip_runtime.h>
#include <math.h>

#define NSNPS  500000
#define NGENES 20000
#define NNODES 600000
#define NEDGES 320000
#define BB     16
#define NFILT  8

// rsqrt(1 + 1e-5)
#define BN_SCALE 0.99999500003749968f

__device__ __forceinline__ float gelu_erf(float x) {
    return 0.5f * x * (1.0f + erff(x * 0.70710678118654752f));
}
__device__ __forceinline__ float sigmoidf_(float x) {
    return 1.0f / (1.0f + expf(-x));
}

// ---------------------------------------------------------------------------
// filters [NFILT, NSNPS] -> filtersT [NSNPS, NFILT]   (coalesced reads)
__global__ __launch_bounds__(256) void k_transpose(const float* __restrict__ filters,
                                                   float* __restrict__ filtersT) {
    int idx = blockIdx.x * 256 + threadIdx.x;
    if (idx >= NFILT * NSNPS) return;
    int f = idx / NSNPS;
    int n = idx - f * NSNPS;
    filtersT[n * NFILT + f] = filters[idx];
}

// ---------------------------------------------------------------------------
// snp [BB, NSNPS] -> snpT [NSNPS, BB]  (coalesced reads, 64B/thread writes)
__global__ __launch_bounds__(256) void k_snpT(const float* __restrict__ snp,
                                              float* __restrict__ snpT) {
    int n = blockIdx.x * 256 + threadIdx.x;
    if (n >= NSNPS) return;
    float v[16];
    #pragma unroll
    for (int b = 0; b < 16; b++) v[b] = snp[(size_t)b * NSNPS + n];
    float4* dst = (float4*)(snpT + (size_t)n * 16);
    dst[0] = make_float4(v[0], v[1], v[2], v[3]);
    dst[1] = make_float4(v[4], v[5], v[6], v[7]);
    dst[2] = make_float4(v[8], v[9], v[10], v[11]);
    dst[3] = make_float4(v[12], v[13], v[14], v[15]);
}

// ---------------------------------------------------------------------------
// node_off[g] = lower_bound(gene_of_node, g), g in [0, NGENES]
__global__ __launch_bounds__(256) void k_node_off(const int* __restrict__ gene_of_node,
                                                  int* __restrict__ node_off) {
    int g = blockIdx.x * 256 + threadIdx.x;
    if (g > NGENES) return;
    int lo = 0, hi = NNODES;
    while (lo < hi) {
        int mid = (lo + hi) >> 1;
        if (gene_of_node[mid] < g) lo = mid + 1; else hi = mid;
    }
    node_off[g] = lo;
}

// ---------------------------------------------------------------------------
__global__ __launch_bounds__(256) void k_zero(int* __restrict__ deg, float* __restrict__ g_h) {
    int i = blockIdx.x * 256 + threadIdx.x;
    if (i < NGENES) deg[i] = 0;
    if (i < BB * NFILT) g_h[i] = 0.0f;
}

__global__ __launch_bounds__(256) void k_deg(const int* __restrict__ edge_dst,
                                             int* __restrict__ deg) {
    int e = blockIdx.x * 256 + threadIdx.x;
    if (e >= NEDGES) return;
    atomicAdd(&deg[edge_dst[e]], 1);
}

// single-block exclusive scan over deg[NGENES] -> csr_off, cursor
__global__ __launch_bounds__(1024) void k_scan(const int* __restrict__ deg,
                                               int* __restrict__ csr_off,
                                               int* __restrict__ cursor) {
    __shared__ int sums[1024];
    int t = threadIdx.x;
    const int CH = (NGENES + 1023) / 1024;   // 20
    int base = t * CH;
    int s = 0;
    for (int i = 0; i < CH; i++) {
        int idx = base + i;
        if (idx < NGENES) s += deg[idx];
    }
    sums[t] = s;
    __syncthreads();
    for (int off = 1; off < 1024; off <<= 1) {
        int v = (t >= off) ? sums[t - off] : 0;
        __syncthreads();
        sums[t] += v;
        __syncthreads();
    }
    int run = (t == 0) ? 0 : sums[t - 1];
    for (int i = 0; i < CH; i++) {
        int idx = base + i;
        if (idx < NGENES) {
            csr_off[idx] = run;
            cursor[idx]  = run;
            run += deg[idx];
        }
    }
    if (t == 1023) csr_off[NGENES] = sums[1023];
}

__global__ __launch_bounds__(256) void k_scatter(const int* __restrict__ edge_src,
                                                 const int* __restrict__ edge_dst,
                                                 int* __restrict__ cursor,
                                                 int* __restrict__ csr_src) {
    int e = blockIdx.x * 256 + threadIdx.x;
    if (e >= NEDGES) return;
    int p = atomicAdd(&cursor[edge_dst[e]], 1);
    csr_src[p] = edge_src[e];
}

// ---------------------------------------------------------------------------
// v2: one wave per gene, ALL 16 batches in the wave.
// lane = b*4 + fpair (b=lane>>2, fpair=lane&3; f = 2*fpair, 2*fpair+1).
// Per node: one 64B snpT line + one 64B filtersT line, ids broadcast by shfl.
__global__ __launch_bounds__(256) void k_snp2gene_v2(const float* __restrict__ snpT,
                                                     const int* __restrict__ snp_ids,
                                                     const int* __restrict__ node_off,
                                                     const float* __restrict__ filtersT,
                                                     float* __restrict__ h) {
    int g = blockIdx.x * 4 + (threadIdx.x >> 6);         // one wave per gene
    int lane = threadIdx.x & 63;
    int b = lane >> 2;
    int fpair = lane & 3;
    int s = node_off[g], e = node_off[g + 1];
    float2 acc = make_float2(0.0f, 0.0f);
    for (int base = s; base < e; base += 64) {
        int myid = (base + lane < e) ? snp_ids[base + lane] : 0;
        int n = e - base; if (n > 64) n = 64;
        for (int j = 0; j < n; j++) {
            int sid = __shfl(myid, j, 64);
            float val = snpT[(size_t)sid * 16 + b];
            float2 flt = *(const float2*)(filtersT + (size_t)sid * 8 + 2 * fpair);
            acc.x += val * flt.x;
            acc.y += val * flt.y;
        }
    }
    *(float2*)(h + ((size_t)(b * NGENES + g)) * NFILT + 2 * fpair) = acc;
}

// ---------------------------------------------------------------------------
// v1 fallback (used only if ws_size too small for snpT)
__global__ __launch_bounds__(256) void k_snp2gene(const float* __restrict__ snp,
                                                  const int* __restrict__ snp_ids,
                                                  const int* __restrict__ node_off,
                                                  const float* __restrict__ filtersT,
                                                  float* __restrict__ h) {
    int wid = blockIdx.x * 4 + (threadIdx.x >> 6);
    int g = wid >> 4;
    int b = wid & 15;
    int lane = threadIdx.x & 63;
    int f = lane & 7;
    int sub = lane >> 3;
    int s = node_off[g], e = node_off[g + 1];
    const float* snpb = snp + (size_t)b * NSNPS;
    float acc = 0.0f;
    for (int i = s + sub; i < e; i += 8) {
        int sid = snp_ids[i];
        acc += snpb[sid] * filtersT[sid * NFILT + f];
    }
    acc += __shfl_xor(acc, 8, 64);
    acc += __shfl_xor(acc, 16, 64);
    acc += __shfl_xor(acc, 32, 64);
    if (lane < 8) h[((size_t)(b * NGENES + g)) * NFILT + f] = acc;
}

// ---------------------------------------------------------------------------
// Fused GIN layer: agg (CSR gather) + (1+eps)*h + MLP(8->16->8) + BN + GELU
__global__ __launch_bounds__(256) void k_gin(const float* __restrict__ hin,
                                             float* __restrict__ hout,
                                             const int* __restrict__ csr_off,
                                             const int* __restrict__ csr_src,
                                             const float* __restrict__ eps_l,
                                             const float* __restrict__ W1,
                                             const float* __restrict__ b1,
                                             const float* __restrict__ g1,
                                             const float* __restrict__ bt1,
                                             const float* __restrict__ W2,
                                             const float* __restrict__ b2,
                                             const float* __restrict__ g2,
                                             const float* __restrict__ bt2) {
    __shared__ float sW1[128], sb1[16], sg1[16], sbt1[16];
    __shared__ float sW2[128], sb2[8], sg2[8], sbt2[8];
    int t = threadIdx.x;
    if (t < 128) { sW1[t] = W1[t]; sW2[t] = W2[t]; }
    if (t < 16)  { sb1[t] = b1[t]; sg1[t] = g1[t]; sbt1[t] = bt1[t]; }
    if (t < 8)   { sb2[t] = b2[t]; sg2[t] = g2[t]; sbt2[t] = bt2[t]; }
    __syncthreads();

    int g = blockIdx.x * 256 + t;
    if (g >= NGENES) return;
    int b = blockIdx.y;

    float z[8];
    const float4* hr4 = (const float4*)(hin + ((size_t)b * NGENES + g) * NFILT);
    float4 h0 = hr4[0], h1 = hr4[1];
    float epsv = 1.0f + eps_l[0];
    z[0] = epsv * h0.x; z[1] = epsv * h0.y; z[2] = epsv * h0.z; z[3] = epsv * h0.w;
    z[4] = epsv * h1.x; z[5] = epsv * h1.y; z[6] = epsv * h1.z; z[7] = epsv * h1.w;

    int s = csr_off[g], e = csr_off[g + 1];
    const float* hb = hin + (size_t)b * NGENES * NFILT;
    for (int k = s; k < e; k++) {
        const float4* hs4 = (const float4*)(hb + (size_t)csr_src[k] * NFILT);
        float4 v0 = hs4[0], v1 = hs4[1];
        z[0] += v0.x; z[1] += v0.y; z[2] += v0.z; z[3] += v0.w;
        z[4] += v1.x; z[5] += v1.y; z[6] += v1.z; z[7] += v1.w;
    }

    float o[8];
    #pragma unroll
    for (int f = 0; f < 8; f++) o[f] = sb2[f];
    #pragma unroll
    for (int j = 0; j < 16; j++) {
        float s1 = sb1[j];
        #pragma unroll
        for (int i = 0; i < 8; i++) s1 += z[i] * sW1[i * 16 + j];
        s1 = s1 * BN_SCALE * sg1[j] + sbt1[j];
        s1 = gelu_erf(s1);
        #pragma unroll
        for (int f = 0; f < 8; f++) o[f] += s1 * sW2[j * 8 + f];
    }
    float* ho = hout + ((size_t)b * NGENES + g) * NFILT;
    #pragma unroll
    for (int f = 0; f < 8; f++) {
        float v = o[f] * BN_SCALE * sg2[f] + sbt2[f];
        ho[f] = gelu_erf(v);
    }
}

// ---------------------------------------------------------------------------
// Attentive readout: w = sigmoid((h@Wk+bk)@Wq); v = h@Wv+bv; g_h += v*w
__global__ __launch_bounds__(256) void k_readout(const float* __restrict__ h,
                                                 const float* __restrict__ Wk,
                                                 const float* __restrict__ bk,
                                                 const float* __restrict__ Wq,
                                                 const float* __restrict__ Wv,
                                                 const float* __restrict__ bv,
                                                 float* __restrict__ w_out,
                                                 float* __restrict__ g_h) {
    __shared__ float sWk[64], sWv[64], sbk[8], sbv[8], sWq[8];
    __shared__ float lds[4][8];
    int t = threadIdx.x;
    if (t < 64) { sWk[t] = Wk[t]; sWv[t] = Wv[t]; }
    if (t < 8)  { sbk[t] = bk[t]; sbv[t] = bv[t]; sWq[t] = Wq[t]; }
    __syncthreads();

    int g = blockIdx.x * 256 + t;
    int b = blockIdx.y;
    float contrib[8];
    #pragma unroll
    for (int f = 0; f < 8; f++) contrib[f] = 0.0f;

    if (g < NGENES) {
        const float* hr = h + ((size_t)b * NGENES + g) * NFILT;
        float hv[8];
        #pragma unroll
        for (int i = 0; i < 8; i++) hv[i] = hr[i];
        float q = 0.0f;
        #pragma unroll
        for (int j = 0; j < 8; j++) {
            float key = sbk[j];
            #pragma unroll
            for (int i = 0; i < 8; i++) key += hv[i] * sWk[i * 8 + j];
            q += key * sWq[j];
        }
        float w = sigmoidf_(q);
        w_out[(size_t)b * NGENES + g] = w;
        #pragma unroll
        for (int f = 0; f < 8; f++) {
            float v = sbv[f];
            #pragma unroll
            for (int i = 0; i < 8; i++) v += hv[i] * sWv[i * 8 + f];
            contrib[f] = v * w;
        }
    }
    #pragma unroll
    for (int f = 0; f < 8; f++) {
        #pragma unroll
        for (int m = 1; m < 64; m <<= 1) contrib[f] += __shfl_xor(contrib[f], m, 64);
    }
    int wave = t >> 6, lane = t & 63;
    if (lane < 8) lds[wave][lane] = contrib[lane];
    __syncthreads();
    if (t < 8) {
        float s = lds[0][t] + lds[1][t] + lds[2][t] + lds[3][t];
        atomicAdd(&g_h[b * NFILT + t], s);
    }
}

// ---------------------------------------------------------------------------
// Head MLP: g_h[16,8] -> 64 -> 16 -> 1, single block
__global__ __launch_bounds__(1024) void k_head(const float* __restrict__ g_h,
                                               const float* __restrict__ Wp1, const float* __restrict__ bp1,
                                               const float* __restrict__ gp1, const float* __restrict__ btp1,
                                               const float* __restrict__ Wp2, const float* __restrict__ bp2,
                                               const float* __restrict__ gp2, const float* __restrict__ btp2,
                                               const float* __restrict__ Wp3, const float* __restrict__ bp3,
                                               float* __restrict__ preds) {
    __shared__ float sgh[128];
    __shared__ float z1[16 * 64];
    __shared__ float z2[16 * 16];
    int t = threadIdx.x;
    if (t < 128) sgh[t] = g_h[t];
    __syncthreads();
    {
        int b = t >> 6, j = t & 63;
        float s = bp1[j];
        #pragma unroll
        for (int k = 0; k < 8; k++) s += sgh[b * 8 + k] * Wp1[k * 64 + j];
        s = s * BN_SCALE * gp1[j] + btp1[j];
        z1[b * 64 + j] = gelu_erf(s);
    }
    __syncthreads();
    if (t < 256) {
        int b = t >> 4, j = t & 15;
        float s = bp2[j];
        for (int k = 0; k < 64; k++) s += z1[b * 64 + k] * Wp2[k * 16 + j];
        s = s * BN_SCALE * gp2[j] + btp2[j];
        z2[b * 16 + j] = gelu_erf(s);
    }
    __syncthreads();
    if (t < 16) {
        float s = bp3[0];
        #pragma unroll
        for (int k = 0; k < 16; k++) s += z2[t * 16 + k] * Wp3[k];
        preds[t] = s;
    }
}

// ---------------------------------------------------------------------------
__global__ __launch_bounds__(256) void k_copy4(const float4* __restrict__ src,
                                               float4* __restrict__ dst, int n4) {
    int i = blockIdx.x * 256 + threadIdx.x;
    if (i < n4) dst[i] = src[i];
}

// ---------------------------------------------------------------------------
extern "C" void kernel_launch(void* const* d_in, const int* in_sizes, int n_in,
                              void* d_out, int out_size, void* d_ws, size_t ws_size,
                              hipStream_t stream) {
    const float* snp          = (const float*)d_in[0];
    const int*   snp_ids      = (const int*)  d_in[1];
    const int*   gene_of_node = (const int*)  d_in[2];
    const int*   edge_src     = (const int*)  d_in[3];
    const int*   edge_dst     = (const int*)  d_in[4];
    const float* filters      = (const float*)d_in[5];
    const float* eps          = (const float*)d_in[6];
    const float* W1  = (const float*)d_in[7];
    const float* b1  = (const float*)d_in[8];
    const float* g1  = (const float*)d_in[9];
    const float* bt1 = (const float*)d_in[10];
    const float* W2  = (const float*)d_in[11];
    const float* b2  = (const float*)d_in[12];
    const float* g2  = (const float*)d_in[13];
    const float* bt2 = (const float*)d_in[14];
    const float* Wk  = (const float*)d_in[15];
    const float* bk  = (const float*)d_in[16];
    const float* Wq  = (const float*)d_in[17];
    const float* Wv  = (const float*)d_in[18];
    const float* bv  = (const float*)d_in[19];
    const float* Wp1 = (const float*)d_in[20];
    const float* bp1 = (const float*)d_in[21];
    const float* gp1 = (const float*)d_in[22];
    const float* btp1= (const float*)d_in[23];
    const float* Wp2 = (const float*)d_in[24];
    const float* bp2 = (const float*)d_in[25];
    const float* gp2 = (const float*)d_in[26];
    const float* btp2= (const float*)d_in[27];
    const float* Wp3 = (const float*)d_in[28];
    const float* bp3 = (const float*)d_in[29];

    float* out        = (float*)d_out;
    float* out_preds  = out;
    float* out_filt   = out + 16;
    float* out_w      = out + 16 + NFILT * NSNPS;

    // filtersT scratch lives in the d_out filters region (exactly 16 MB);
    // overwritten by the real copy at the very end.
    float* filtersT = out_filt;

    // ---- workspace layout (v2): snpT aliases h1 (snpT dead after snp2gene)
    char* ws = (char*)d_ws;
    size_t off = 0;
    float* h0   = (float*)(ws + off); off += (size_t)BB * NGENES * NFILT * 4;   // 10.24 MB
    float* snpT = (float*)(ws + off);
    float* h1   = (float*)(ws + off); off += (size_t)NSNPS * BB * 4;            // 32 MB (>= h1)
    int* node_off = (int*)(ws + off); off += ((NGENES + 1) * 4 + 255) / 256 * 256;
    int* deg      = (int*)(ws + off); off += (NGENES * 4 + 255) / 256 * 256;
    int* csr_off  = (int*)(ws + off); off += ((NGENES + 1) * 4 + 255) / 256 * 256;
    int* cursor   = (int*)(ws + off); off += (NGENES * 4 + 255) / 256 * 256;
    int* csr_src  = (int*)(ws + off); off += (size_t)NEDGES * 4;
    float* g_h    = (float*)(ws + off); off += 256;
    bool v2 = (ws_size >= off);

    if (!v2) {
        // fallback layout (v1, ~24 MB)
        off = 0;
        h0 = (float*)(ws + off); off += (size_t)BB * NGENES * NFILT * 4;
        h1 = (float*)(ws + off); off += (size_t)BB * NGENES * NFILT * 4;
        node_off = (int*)(ws + off); off += ((NGENES + 1) * 4 + 255) / 256 * 256;
        deg      = (int*)(ws + off); off += (NGENES * 4 + 255) / 256 * 256;
        csr_off  = (int*)(ws + off); off += ((NGENES + 1) * 4 + 255) / 256 * 256;
        cursor   = (int*)(ws + off); off += (NGENES * 4 + 255) / 256 * 256;
        csr_src  = (int*)(ws + off); off += (size_t)NEDGES * 4;
        g_h      = (float*)(ws + off); off += 256;
    }

    // 1. transposes
    k_transpose<<<(NFILT * NSNPS + 255) / 256, 256, 0, stream>>>(filters, filtersT);
    if (v2) k_snpT<<<(NSNPS + 255) / 256, 256, 0, stream>>>(snp, snpT);
    // 2. gene node offsets
    k_node_off<<<(NGENES + 1 + 255) / 256, 256, 0, stream>>>(gene_of_node, node_off);
    // 3. CSR build
    k_zero<<<(NGENES + 255) / 256, 256, 0, stream>>>(deg, g_h);
    k_deg<<<(NEDGES + 255) / 256, 256, 0, stream>>>(edge_dst, deg);
    k_scan<<<1, 1024, 0, stream>>>(deg, csr_off, cursor);
    k_scatter<<<(NEDGES + 255) / 256, 256, 0, stream>>>(edge_src, edge_dst, cursor, csr_src);
    // 4. SNP -> gene readout
    if (v2)
        k_snp2gene_v2<<<NGENES / 4, 256, 0, stream>>>(snpT, snp_ids, node_off, filtersT, h0);
    else
        k_snp2gene<<<(NGENES * BB) / 4, 256, 0, stream>>>(snp, snp_ids, node_off, filtersT, h0);
    // 5. GIN layers
    dim3 grid_row((NGENES + 255) / 256, BB);
    k_gin<<<grid_row, 256, 0, stream>>>(h0, h1, csr_off, csr_src, eps + 0,
                                        W1 + 0 * 128, b1 + 0 * 16, g1 + 0 * 16, bt1 + 0 * 16,
                                        W2 + 0 * 128, b2 + 0 * 8, g2 + 0 * 8, bt2 + 0 * 8);
    k_gin<<<grid_row, 256, 0, stream>>>(h1, h0, csr_off, csr_src, eps + 1,
                                        W1 + 1 * 128, b1 + 1 * 16, g1 + 1 * 16, bt1 + 1 * 16,
                                        W2 + 1 * 128, b2 + 1 * 8, g2 + 1 * 8, bt2 + 1 * 8);
    // 6. attentive readout
    k_readout<<<grid_row, 256, 0, stream>>>(h0, Wk, bk, Wq, Wv, bv, out_w, g_h);
    // 7. head MLP
    k_head<<<1, 1024, 0, stream>>>(g_h, Wp1, bp1, gp1, btp1, Wp2, bp2, gp2, btp2, Wp3, bp3, out_preds);
    // 8. filters passthrough (overwrites filtersT scratch)
    k_copy4<<<(NFILT * NSNPS / 4 + 255) / 256, 256, 0, stream>>>((const float4*)filters,
                                                                 (float4*)out_filt,
                                                                 NFILT * NSNPS / 4);
}